// Round 7
// baseline (254.197 us; speedup 1.0000x reference)
//
#include <hip/hip_runtime.h>
#include <stdint.h>

#define TT 1024
#define AL 0.05f
#define OM 0.95f
#define STRD 408   // padded [c][.] row stride
#define LOG2E 1.4426950408889634f

typedef short s4v __attribute__((ext_vector_type(4)));
typedef short s8v __attribute__((ext_vector_type(8)));
typedef float f4v __attribute__((ext_vector_type(4)));
typedef float f16v __attribute__((ext_vector_type(16)));
typedef int   i2v __attribute__((ext_vector_type(2)));

#define MF32(a,b,c) __builtin_amdgcn_mfma_f32_32x32x16_bf16(a,b,c,0,0,0)
#define MF16(a,b,c) __builtin_amdgcn_mfma_f32_16x16x32_bf16(a,b,c,0,0,0)
// fp8 (OCP e4m3) MFMAs — same shapes, same C/D layout as bf16 (shape-determined)
#define MFP32(a,b,c) __builtin_amdgcn_mfma_f32_32x32x16_fp8_fp8(a,b,c,0,0,0)
#define MFP16(a,b,c) __builtin_amdgcn_mfma_f32_16x16x32_fp8_fp8(a,b,c,0,0,0)

#if __has_builtin(__builtin_amdgcn_exp2f)
#define E2(x) __builtin_amdgcn_exp2f(x)
#else
#define E2(x) exp2f(x)
#endif

__device__ __forceinline__ uint16_t f2bf(float f){ union{float f;uint32_t i;}t; t.f=f; return (uint16_t)((t.i + 0x7fffu + ((t.i>>16)&1u))>>16); }
__device__ __forceinline__ float bf2f(uint16_t h){ union{uint32_t i;float f;}t; t.i=((uint32_t)h)<<16; return t.f; }
__device__ __forceinline__ float bfLO(uint32_t u){ union{uint32_t i;float f;}t; t.i=u<<16; return t.f; }
__device__ __forceinline__ float bfHI(uint32_t u){ union{uint32_t i;float f;}t; t.i=u&0xffff0000u; return t.f; }
__device__ __forceinline__ uint32_t cvtpk(float lo, float hi){ uint32_t r; asm("v_cvt_pk_bf16_f32 %0, %1, %2" : "=v"(r) : "v"(lo), "v"(hi)); return r; }
__device__ __forceinline__ void pl32swap(uint32_t &x, uint32_t &y){
#if __has_builtin(__builtin_amdgcn_permlane32_swap)
  i2v rr = __builtin_amdgcn_permlane32_swap((int)x, (int)y, false, false);
  x = (uint32_t)rr.x; y = (uint32_t)rr.y;
#else
  asm("v_permlane32_swap_b32 %0, %1" : "+v"(x), "+v"(y));
#endif
}
__device__ __forceinline__ float ftanh(float x){ float t = E2(2.885390081777927f*x); return __builtin_fmaf(-2.f, __builtin_amdgcn_rcpf(1.f + t), 1.f); }
__device__ __forceinline__ s8v ld8(const uint16_t* p){ return *(const s8v*)p; }

// software e4m3fn fallback (only if builtin missing)
__device__ __forceinline__ uint32_t sw1fp8(float f){
  union{float f;uint32_t u;}t; t.f=f;
  uint32_t sgn=(t.u>>24)&0x80u; uint32_t a=t.u&0x7fffffffu;
  union{uint32_t u;float f;}af; af.u=a;
  if(af.f>448.f) return sgn|0x7eu;
  if(af.f<0.001953125f){ int q=(int)(af.f*512.f+0.5f); if(q>7)q=7; return sgn|(uint32_t)q; }
  uint32_t lsb=(a>>20)&1u; a+=0x0007ffffu+lsb;
  int ex=(int)(a>>23)-120; uint32_t man=(a>>20)&7u;
  if(ex>15||(ex==15&&man==7u)) return sgn|0x7eu;
  if(ex<=0){ int q=(int)(af.f*512.f+0.5f); if(q>7)q=7; return sgn|(uint32_t)q; }
  return sgn|((uint32_t)ex<<3)|man;
}
__device__ __forceinline__ uint32_t pk4fp8(float a,float b,float c,float d){
#if __has_builtin(__builtin_amdgcn_cvt_pk_fp8_f32)
  int v = __builtin_amdgcn_cvt_pk_fp8_f32(a,b,0,false);
  v = __builtin_amdgcn_cvt_pk_fp8_f32(c,d,v,true);
  return (uint32_t)v;
#else
  return sw1fp8(a) | (sw1fp8(b)<<8) | (sw1fp8(c)<<16) | (sw1fp8(d)<<24);
#endif
}
__device__ __forceinline__ s8v packw8(float4 f0, float4 f1){
  union{uint32_t d[4]; s8v v8;} A;
  A.d[0]=cvtpk(f0.x,f0.y); A.d[1]=cvtpk(f0.z,f0.w);
  A.d[2]=cvtpk(f1.x,f1.y); A.d[3]=cvtpk(f1.z,f1.w);
  return A.v8;
}

#define ROWF(e2) (((e2)&3) + 8*((e2)>>2) + 4*h2)
// bf16 [v][32] swizzle (u16 domain)
#define VXA(row,off) ((((row)<<5) + (off)) ^ (((row)&7)<<3))
// fp8 [v][32B] swizzle (byte domain): XOR byte-bits 4-5 with row&3 -> conflict-light b64
#define VX8(row,b) ((((row)<<5) + (b)) ^ (((row)&3)<<4))

// staging buffer for output transpose
__device__ __align__(16) float gStage[32*12*12800];

// ---- S map: 39,712 u16 = 79,424 B  (<= 81,664 B -> 2 blocks/CU) ----
// bytes:  X1B=0 (fp8 x1, 12800B)  X2B=12800 (fp8 x2, 12800B)
// u16:    XCV=12800 (bf16 X -> H1 in place, 13056)  GCV=25856 (XT / stats / G1, 13056)
//         RINV=38912 (400)  CINV=39312 (400)
// MLP:    Hv=[v][32] bf16 at u16 0 (over x1/x2);  F2V=[v][32] bf16 at u16 12800 (over XCV)
#define X1B 0
#define X2B 12800
#define XCV 12800
#define GCV 25856
#define XTU 25856
#define RINV 38912
#define CINV 39312
#define HV 0
#define F2V 12800

__global__ __launch_bounds__(TT) void dymix(
    const float* __restrict__ x,
    const float* __restrict__ w1, const float* __restrict__ b1,
    const float* __restrict__ w2, const float* __restrict__ b2,
    const float* __restrict__ wm1, const float* __restrict__ bm1,
    const float* __restrict__ wm2, const float* __restrict__ bm2)
{
  __shared__ __align__(16) uint16_t S[39712];
  uint8_t* S8 = (uint8_t*)S;

  const int blk = blockIdx.x;
  const int xcd = blk & 7, slot = blk >> 3;
  const int n = xcd*4 + slot/12;
  const int l = slot - (slot/12)*12;
  const int t = threadIdx.x;
  const int wv = t >> 6;
  const int lane = t & 63;
  const int q  = lane >> 4;
  const int r  = lane & 15;
  const int h2 = lane >> 5;
  const int m32 = lane & 31;
  const long xbase = (long)n*153600 + l;

  // ---------- Phase 0: stage X -> XCV [c][408] ----------
  for (int i = t; i < 12800; i += TT) {
    int c = i / 400, v = i - c*400;
    S[XCV + c*STRD + v] = f2bf(x[xbase + (long)i*12]);
  }
  __syncthreads();

  // ---------- XT (swizzled [v][32] bf16) into GCV region ----------
  for (int i = t; i < 12800; i += TT) { int v = i>>5, c = i&31; S[XTU + VXA(v,c)] = S[XCV + c*STRD + v]; }
  __syncthreads();

  // ---------- Phase L: x1 = log2e*tanh(W1 X + b1) fp8, x2 = tanh(W2 X + b2) fp8.
  // Weights/biases come straight from GLOBAL into registers (no LDS staging). ----------
  #pragma unroll
  for (int j = 0; j < 2; ++j) {
    int u = wv + 16*j;
    if (u < 24) {
      int nt = u >> 1, li = u & 1;
      const float* wsrc = li ? w2 : w1;
      const float* bsrc = li ? b2 : b1;
      uint8_t* dst8 = S8 + (li ? X2B : X1B);
      const float osc = li ? 1.f : LOG2E;
      f16v z = {};
      #pragma unroll
      for (int kk = 0; kk < 2; ++kk) {
        const float* wp = wsrc + m32*32 + kk*16 + h2*8;
        s8v a = packw8(*(const float4*)(wp), *(const float4*)(wp+4));
        s8v b = ld8(S + XTU + VXA(nt*32 + m32, kk*16 + h2*8));
        z = MF32(a, b, z);
      }
      int v = nt*32 + m32;
      #pragma unroll
      for (int g = 0; g < 4; ++g) {
        float4 bv = *(const float4*)(bsrc + 8*g + 4*h2);
        float p0 = ftanh(z[4*g+0] + bv.x) * osc;
        float p1 = ftanh(z[4*g+1] + bv.y) * osc;
        float p2 = ftanh(z[4*g+2] + bv.z) * osc;
        float p3 = ftanh(z[4*g+3] + bv.w) * osc;
        *(uint32_t*)(dst8 + VX8(v, 8*g + 4*h2)) = pk4fp8(p0,p1,p2,p3);
      }
    } else if (u < 28) {
      int li = (u-24)>>1, mt = u&1;
      const float* wsrc = li ? w2 : w1;
      const float* bsrc = li ? b2 : b1;
      uint8_t* dst8 = S8 + (li ? X2B : X1B);
      const float osc = li ? 1.f : LOG2E;
      const float* wp = wsrc + (mt*16 + r)*32 + q*8;
      s8v a = packw8(*(const float4*)(wp), *(const float4*)(wp+4));
      s8v b = ld8(S + XTU + VXA(384 + r, q*8));
      f4v z4 = {}; z4 = MF16(a, b, z4);
      float4 bv = *(const float4*)(bsrc + mt*16 + q*4);
      float p0 = ftanh(z4[0] + bv.x) * osc;
      float p1 = ftanh(z4[1] + bv.y) * osc;
      float p2 = ftanh(z4[2] + bv.z) * osc;
      float p3 = ftanh(z4[3] + bv.w) * osc;
      *(uint32_t*)(dst8 + VX8(384 + r, mt*16 + q*4)) = pk4fp8(p0,p1,p2,p3);
    }
  }
  // preload MLP X b-frags (bf16) from XT before it dies
  s8v xf0, xf1, xft;
  {
    int m0 = (wv < 12) ? wv : 0;
    xf0 = ld8(S + XTU + VXA(m0*32 + m32, h2*8));
    xf1 = ld8(S + XTU + VXA(m0*32 + m32, 16 + h2*8));
    xft = ld8(S + XTU + VXA(384 + r, q*8));
  }
  __syncthreads();

  // ---------- Stats: rowsum/colsum of exp2(A') — fp8 QK^T ----------
  float* rsf = (float*)(S + GCV);
  float* csf = rsf + 400;
  for (int i = t; i < 400; i += TT) csf[i] = 0.f;
  __syncthreads();
  {
    long av8[2]; f4v rac[2] = {{},{}};
    #pragma unroll
    for (int jj = 0; jj < 2; ++jj) { int vt = wv + 16*jj; if (vt < 25) av8[jj] = *(const long*)(S8 + X1B + VX8(vt*16 + r, q*8)); }
    for (int wt = 0; wt < 25; ++wt) {
      long b8 = *(const long*)(S8 + X2B + VX8(wt*16 + r, q*8));
      float cp = 0.f;
      #pragma unroll
      for (int jj = 0; jj < 2; ++jj) {
        int vt = wv + 16*jj;
        if (vt < 25) {
          f4v z = {}; z = MFP16(av8[jj], b8, z);
          #pragma unroll
          for (int e = 0; e < 4; ++e) { float ev = E2(z[e]); rac[jj][e] += ev; cp += ev; }
        }
      }
      cp += __shfl_xor(cp, 16); cp += __shfl_xor(cp, 32);
      if (q == 0) atomicAdd(&csf[wt*16 + r], cp);
    }
    #pragma unroll
    for (int jj = 0; jj < 2; ++jj) {
      int vt = wv + 16*jj;
      if (vt < 25) {
        #pragma unroll
        for (int e = 0; e < 4; ++e) {
          float s = rac[jj][e];
          s += __shfl_xor(s,1); s += __shfl_xor(s,2); s += __shfl_xor(s,4); s += __shfl_xor(s,8);
          if (r == 0) rsf[vt*16 + q*4 + e] = s;
        }
      }
    }
  }
  __syncthreads();
  for (int i = t; i < 400; i += TT) { S[RINV + i] = f2bf(1.f/rsf[i]); S[CINV + i] = f2bf(1.f/csf[i]); }
  __syncthreads();

  // ---------- Diffusion: r6 structure (register P everywhere); QK^T inputs fp8.
  // H1 is written IN PLACE over X (XCV) via a split read/barrier/write epilogue. ----------
  f16v acc[2];
  for (int step = 0; step < 2; ++step) {
    { f16v zv = {}; acc[0]=zv; acc[1]=zv; }
    const uint16_t* AH = S + XCV;                     // X (step0) / H1 (step1), same region
    const uint16_t* AG = S + (step ? GCV : XCV);
    for (int sb = 0; sb < 13; ++sb) {
      const int vbase = sb*32;
      const bool lastsb = (sb == 12);
      const int kmax = lastsb ? 1 : 2;
      s8v fr[2][2];
      uint2 td0[2], td1[2];
      // ---- T: fp8 z, pack P in registers ----
      #pragma unroll
      for (int jj = 0; jj < 2; ++jj) {
        int g = wv + 16*jj;
        if (g >= 26) continue;
        int chain = (g < 13) ? 0 : 1;
        int uu = g - 13*chain;
        const uint8_t* sa8 = S8 + (chain ? X2B : X1B);
        const uint8_t* sb8 = S8 + (chain ? X1B : X2B);
        const int scl = chain ? CINV : RINV;
        if (uu < 12) {
          long a0 = *(const long*)(sa8 + VX8(vbase + m32, h2*8));
          long a1 = *(const long*)(sa8 + VX8(vbase + m32, 16 + h2*8));
          long b0 = *(const long*)(sb8 + VX8(uu*32 + m32, h2*8));
          long b1 = *(const long*)(sb8 + VX8(uu*32 + m32, 16 + h2*8));
          f16v z = {}; z = MFP32(a0, b0, z); z = MFP32(a1, b1, z);
          #pragma unroll
          for (int k = 0; k < 2; ++k) {
            if (k < kmax) {
              const uint16_t* spt = S + scl + vbase + 16*k + 4*h2;
              uint32_t sAB = *(const uint32_t*)(spt);
              uint32_t sCD = *(const uint32_t*)(spt + 2);
              uint32_t sEF = *(const uint32_t*)(spt + 8);
              uint32_t sGH = *(const uint32_t*)(spt + 10);
              uint32_t C0 = cvtpk(E2(z[8*k+0])*bfLO(sAB), E2(z[8*k+1])*bfHI(sAB));
              uint32_t C1 = cvtpk(E2(z[8*k+2])*bfLO(sCD), E2(z[8*k+3])*bfHI(sCD));
              uint32_t C2 = cvtpk(E2(z[8*k+4])*bfLO(sEF), E2(z[8*k+5])*bfHI(sEF));
              uint32_t C3 = cvtpk(E2(z[8*k+6])*bfLO(sGH), E2(z[8*k+7])*bfHI(sGH));
              pl32swap(C0, C2);
              pl32swap(C1, C3);
              union { uint32_t d[4]; s8v v8; } F;
              F.d[0] = C0; F.d[1] = C1; F.d[2] = C2; F.d[3] = C3;
              fr[jj][k] = F.v8;
            }
          }
        } else {
          long bT = *(const long*)(sb8 + VX8(384 + r, q*8));
          td1[jj].x = 0u; td1[jj].y = 0u;
          {
            long a = *(const long*)(sa8 + VX8(vbase + r, q*8));
            f4v z4 = {}; z4 = MFP16(a, bT, z4);
            float p0 = E2(z4[0]) * bf2f(S[scl + vbase + q*4 + 0]);
            float p1 = E2(z4[1]) * bf2f(S[scl + vbase + q*4 + 1]);
            float p2 = E2(z4[2]) * bf2f(S[scl + vbase + q*4 + 2]);
            float p3 = E2(z4[3]) * bf2f(S[scl + vbase + q*4 + 3]);
            td0[jj].x = cvtpk(p0,p1); td0[jj].y = cvtpk(p2,p3);
          }
          if (!lastsb) {
            long a = *(const long*)(sa8 + VX8(vbase + 16 + r, q*8));
            f4v z4 = {}; z4 = MFP16(a, bT, z4);
            float p0 = E2(z4[0]) * bf2f(S[scl + vbase + 16 + q*4 + 0]);
            float p1 = E2(z4[1]) * bf2f(S[scl + vbase + 16 + q*4 + 1]);
            float p2 = E2(z4[2]) * bf2f(S[scl + vbase + 16 + q*4 + 2]);
            float p3 = E2(z4[3]) * bf2f(S[scl + vbase + 16 + q*4 + 3]);
            td1[jj].x = cvtpk(p0,p1); td1[jj].y = cvtpk(p2,p3);
          }
        }
      }
      // ---- GEMM (bf16): register frags / shfl exchange for tail ----
      #pragma unroll
      for (int jj = 0; jj < 2; ++jj) {
        int g = wv + 16*jj;
        if (g >= 26) continue;
        int chain = (g < 13) ? 0 : 1;
        int uu = g - 13*chain;
        const uint16_t* Acv = chain ? AG : AH;
        if (uu < 12) {
          #pragma unroll
          for (int k = 0; k < 2; ++k) {
            if (k < kmax) {
              s8v a = ld8(Acv + m32*STRD + vbase + k*16 + h2*8);
              acc[jj] = MF32(a, fr[jj][k], acc[jj]);
            }
          }
        } else {
          const int src0 = (((q<<1)) & 3)*16 + r;
          const int src1 = (((q<<1)+1) & 3)*16 + r;
          uint32_t a0x = (uint32_t)__shfl((int)td0[jj].x, src0);
          uint32_t a0y = (uint32_t)__shfl((int)td0[jj].y, src0);
          uint32_t a1x = (uint32_t)__shfl((int)td1[jj].x, src0);
          uint32_t a1y = (uint32_t)__shfl((int)td1[jj].y, src0);
          uint32_t b0x = (uint32_t)__shfl((int)td0[jj].x, src1);
          uint32_t b0y = (uint32_t)__shfl((int)td0[jj].y, src1);
          uint32_t b1x = (uint32_t)__shfl((int)td1[jj].x, src1);
          uint32_t b1y = (uint32_t)__shfl((int)td1[jj].y, src1);
          const bool hi = (q >= 2);
          union { uint32_t u[4]; s8v v8; } B;
          B.u[0] = hi ? a1x : a0x;
          B.u[1] = hi ? a1y : a0y;
          B.u[2] = hi ? b1x : b0x;
          B.u[3] = hi ? b1y : b0y;
          #pragma unroll
          for (int mt2 = 0; mt2 < 2; ++mt2) {
            int koff = (lastsb && q >= 2) ? 0 : q*8;
            s8v a = ld8(Acv + (mt2*16 + r)*STRD + vbase + koff);
            f4v c4 = { acc[jj][4*mt2+0], acc[jj][4*mt2+1], acc[jj][4*mt2+2], acc[jj][4*mt2+3] };
            c4 = MF16(a, B.v8, c4);
            acc[jj][4*mt2+0]=c4[0]; acc[jj][4*mt2+1]=c4[1]; acc[jj][4*mt2+2]=c4[2]; acc[jj][4*mt2+3]=c4[3];
          }
        }
      }
    } // sb
    __syncthreads();
    if (step == 0) {
      // epilogue phase i (reads only): acc = AL*X + OM*acc
      #pragma unroll
      for (int jj = 0; jj < 2; ++jj) {
        int g = wv + 16*jj;
        if (g >= 26) continue;
        int chain = (g < 13) ? 0 : 1;
        int uu = g - 13*chain;
        if (uu < 12) {
          int w = uu*32 + m32;
          #pragma unroll
          for (int e2 = 0; e2 < 16; ++e2) {
            int c = ROWF(e2);
            acc[jj][e2] = AL*bf2f(S[XCV + c*STRD + w]) + OM*acc[jj][e2];
          }
        } else {
          int w = 384 + r;
          #pragma unroll
          for (int mt2 = 0; mt2 < 2; ++mt2)
            #pragma unroll
            for (int e = 0; e < 4; ++e) {
              int c = mt2*16 + q*4 + e;
              acc[jj][4*mt2+e] = AL*bf2f(S[XCV + c*STRD + w]) + OM*acc[jj][4*mt2+e];
            }
        }
      }
      __syncthreads();
      // epilogue phase ii (writes): H1 -> XCV (in place), G1 -> GCV
      #pragma unroll
      for (int jj = 0; jj < 2; ++jj) {
        int g = wv + 16*jj;
        if (g >= 26) continue;
        int chain = (g < 13) ? 0 : 1;
        int uu = g - 13*chain;
        uint16_t* dst = S + (chain ? GCV : XCV);
        if (uu < 12) {
          int w = uu*32 + m32;
          #pragma unroll
          for (int e2 = 0; e2 < 16; ++e2) { int c = ROWF(e2); dst[c*STRD + w] = f2bf(acc[jj][e2]); }
        } else {
          int w = 384 + r;
          #pragma unroll
          for (int mt2 = 0; mt2 < 2; ++mt2)
            #pragma unroll
            for (int e = 0; e < 4; ++e) { int c = mt2*16 + q*4 + e; dst[c*STRD + w] = f2bf(acc[jj][4*mt2+e]); }
        }
      }
      __syncthreads();
    }
  } // step

  // ---------- MLP: two passes (chain0 -> gStage; chain1 -> add). Weights from global. ----------
  // PREP A: H1 [c][408] -> Hv [v][32] bf16 (over dead fp8 x1/x2)
  for (int i = t; i < 12800; i += TT) { int v = i >> 5, c = i & 31; S[HV + VXA(v,c)] = S[XCV + c*STRD + v]; }
  __syncthreads();
  // H2'v = OM*acc (chain-0 units) -> F2V (over XCV region)
  #pragma unroll
  for (int jj = 0; jj < 2; ++jj) {
    int g = wv + 16*jj;
    if (g >= 13) continue;              // chain 0 only
    int uu = g;
    uint16_t* dst = S + F2V;
    if (uu < 12) {
      int w = uu*32 + m32;
      #pragma unroll
      for (int gg = 0; gg < 4; ++gg) {
        uint2 d;
        d.x = cvtpk(OM*acc[jj][4*gg+0], OM*acc[jj][4*gg+1]);
        d.y = cvtpk(OM*acc[jj][4*gg+2], OM*acc[jj][4*gg+3]);
        *(uint2*)(dst + VXA(w, 8*gg + 4*h2)) = d;
      }
    } else {
      int w = 384 + r;
      #pragma unroll
      for (int mt2 = 0; mt2 < 2; ++mt2) {
        uint2 d;
        d.x = cvtpk(OM*acc[jj][4*mt2+0], OM*acc[jj][4*mt2+1]);
        d.y = cvtpk(OM*acc[jj][4*mt2+2], OM*acc[jj][4*mt2+3]);
        *(uint2*)(dst + VXA(w, mt2*16 + q*4)) = d;
      }
    }
  }
  __syncthreads();

  float* oSl = gStage + (long)(n*12 + l)*12800;
  // ---- PASS A (wm1, + combined bias) ----
  {
    int m = wv;
    if (m < 12) {
      f16v z = {};
      #pragma unroll
      for (int p = 0; p < 3; ++p) {
        #pragma unroll
        for (int kk = 0; kk < 2; ++kk) {
          const float* wp = wm1 + m32*96 + p*32 + kk*16 + h2*8;
          float4 f0 = *(const float4*)(wp), f1 = *(const float4*)(wp+4);
          if (p == 0) {
            const float* wp2 = wm1 + m32*96 + 64 + kk*16 + h2*8;
            float4 g0 = *(const float4*)(wp2), g1 = *(const float4*)(wp2+4);
            f0.x += AL*g0.x; f0.y += AL*g0.y; f0.z += AL*g0.z; f0.w += AL*g0.w;
            f1.x += AL*g1.x; f1.y += AL*g1.y; f1.z += AL*g1.z; f1.w += AL*g1.w;
          }
          s8v a = packw8(f0, f1);
          s8v b = (p == 0) ? (kk ? xf1 : xf0)
                           : ld8(S + (p == 1 ? HV : F2V) + VXA(m*32 + m32, kk*16 + h2*8));
          z = MF32(a, b, z);
        }
      }
      int v = m*32 + m32;
      #pragma unroll
      for (int e2 = 0; e2 < 16; ++e2) { int o = ROWF(e2); oSl[o*400 + v] = z[e2] + bm1[o] + bm2[o]; }
    } else if (m < 14) {
      int mt = m - 12;
      f4v z4 = {};
      #pragma unroll
      for (int p = 0; p < 3; ++p) {
        const float* wp = wm1 + (mt*16 + r)*96 + p*32 + q*8;
        float4 f0 = *(const float4*)(wp), f1 = *(const float4*)(wp+4);
        if (p == 0) {
          const float* wp2 = wm1 + (mt*16 + r)*96 + 64 + q*8;
          float4 g0 = *(const float4*)(wp2), g1 = *(const float4*)(wp2+4);
          f0.x += AL*g0.x; f0.y += AL*g0.y; f0.z += AL*g0.z; f0.w += AL*g0.w;
          f1.x += AL*g1.x; f1.y += AL*g1.y; f1.z += AL*g1.z; f1.w += AL*g1.w;
        }
        s8v a = packw8(f0, f1);
        s8v b = (p == 0) ? xft : ld8(S + (p == 1 ? HV : F2V) + VXA(384 + r, q*8));
        z4 = MF16(a, b, z4);
      }
      #pragma unroll
      for (int e = 0; e < 4; ++e) { int o = mt*16 + q*4 + e; oSl[o*400 + 384 + r] = z4[e] + bm1[o] + bm2[o]; }
    }
  }
  __syncthreads();
  // ---- PREP B: G1 -> Hv ; G2'v (chain-1 units) -> F2V ----
  for (int i = t; i < 12800; i += TT) { int v = i >> 5, c = i & 31; S[HV + VXA(v,c)] = S[GCV + c*STRD + v]; }
  #pragma unroll
  for (int jj = 0; jj < 2; ++jj) {
    int g = wv + 16*jj;
    if (g < 13 || g >= 26) continue;    // chain 1 only
    int uu = g - 13;
    uint16_t* dst = S + F2V;
    if (uu < 12) {
      int w = uu*32 + m32;
      #pragma unroll
      for (int gg = 0; gg < 4; ++gg) {
        uint2 d;
        d.x = cvtpk(OM*acc[jj][4*gg+0], OM*acc[jj][4*gg+1]);
        d.y = cvtpk(OM*acc[jj][4*gg+2], OM*acc[jj][4*gg+3]);
        *(uint2*)(dst + VXA(w, 8*gg + 4*h2)) = d;
      }
    } else {
      int w = 384 + r;
      #pragma unroll
      for (int mt2 = 0; mt2 < 2; ++mt2) {
        uint2 d;
        d.x = cvtpk(OM*acc[jj][4*mt2+0], OM*acc[jj][4*mt2+1]);
        d.y = cvtpk(OM*acc[jj][4*mt2+2], OM*acc[jj][4*mt2+3]);
        *(uint2*)(dst + VXA(w, mt2*16 + q*4)) = d;
      }
    }
  }
  __syncthreads();
  // ---- PASS B (wm2, accumulate into gStage) ----
  {
    int m = wv;
    if (m < 12) {
      f16v z = {};
      #pragma unroll
      for (int p = 0; p < 3; ++p) {
        #pragma unroll
        for (int kk = 0; kk < 2; ++kk) {
          const float* wp = wm2 + m32*96 + p*32 + kk*16 + h2*8;
          float4 f0 = *(const float4*)(wp), f1 = *(const float4*)(wp+4);
          if (p == 0) {
            const float* wp2 = wm2 + m32*96 + 64 + kk*16 + h2*8;
            float4 g0 = *(const float4*)(wp2), g1 = *(const float4*)(wp2+4);
            f0.x += AL*g0.x; f0.y += AL*g0.y; f0.z += AL*g0.z; f0.w += AL*g0.w;
            f1.x += AL*g1.x; f1.y += AL*g1.y; f1.z += AL*g1.z; f1.w += AL*g1.w;
          }
          s8v a = packw8(f0, f1);
          s8v b = (p == 0) ? (kk ? xf1 : xf0)
                           : ld8(S + (p == 1 ? HV : F2V) + VXA(m*32 + m32, kk*16 + h2*8));
          z = MF32(a, b, z);
        }
      }
      int v = m*32 + m32;
      #pragma unroll
      for (int e2 = 0; e2 < 16; ++e2) { int o = ROWF(e2); oSl[o*400 + v] += z[e2]; }
    } else if (m < 14) {
      int mt = m - 12;
      f4v z4 = {};
      #pragma unroll
      for (int p = 0; p < 3; ++p) {
        const float* wp = wm2 + (mt*16 + r)*96 + p*32 + q*8;
        float4 f0 = *(const float4*)(wp), f1 = *(const float4*)(wp+4);
        if (p == 0) {
          const float* wp2 = wm2 + (mt*16 + r)*96 + 64 + q*8;
          float4 g0 = *(const float4*)(wp2), g1 = *(const float4*)(wp2+4);
          f0.x += AL*g0.x; f0.y += AL*g0.y; f0.z += AL*g0.z; f0.w += AL*g0.w;
          f1.x += AL*g1.x; f1.y += AL*g1.y; f1.z += AL*g1.z; f1.w += AL*g1.w;
        }
        s8v a = packw8(f0, f1);
        s8v b = (p == 0) ? xft : ld8(S + (p == 1 ? HV : F2V) + VXA(384 + r, q*8));
        z4 = MF16(a, b, z4);
      }
      #pragma unroll
      for (int e = 0; e < 4; ++e) { int o = mt*16 + q*4 + e; oSl[o*400 + 384 + r] += z4[e]; }
    }
  }
}

// Plain transpose kernel: gStage[n][l][o][v] -> out[n][o][v][l] (both sides coalesced)
__global__ __launch_bounds__(256) void finT(float* __restrict__ out) {
  int idx = blockIdx.x*256 + threadIdx.x;
  int n = idx / 12800, ov = idx - n*12800;
  const float* src = gStage + (long)n*153600 + ov;
  float vals[12];
  #pragma unroll
  for (int l = 0; l < 12; ++l) vals[l] = src[(long)l*12800];
  float4* dst = (float4*)(out + (long)idx*12);
  dst[0] = make_float4(vals[0],vals[1],vals[2],vals[3]);
  dst[1] = make_float4(vals[4],vals[5],vals[6],vals[7]);
  dst[2] = make_float4(vals[8],vals[9],vals[10],vals[11]);
}

extern "C" void kernel_launch(void* const* d_in, const int* in_sizes, int n_in,
                              void* d_out, int out_size, void* d_ws, size_t ws_size,
                              hipStream_t stream) {
  (void)in_sizes; (void)n_in; (void)out_size; (void)d_ws; (void)ws_size;
  dymix<<<dim3(384), dim3(TT), 0, stream>>>(
      (const float*)d_in[0],
      (const float*)d_in[1], (const float*)d_in[2],
      (const float*)d_in[3], (const float*)d_in[4],
      (const float*)d_in[5], (const float*)d_in[6],
      (const float*)d_in[7], (const float*)d_in[8]);
  finT<<<dim3(1600), dim3(256), 0, stream>>>((float*)d_out);
}

// Round 8
// 219.058 us; speedup vs baseline: 1.1604x; 1.1604x over previous
//
#include <hip/hip_runtime.h>
#include <stdint.h>

#define TT 512
#define AL 0.05f
#define OM 0.95f
#define STRD 408   // padded [c][.] row stride
#define LOG2E 1.4426950408889634f

typedef short s4v __attribute__((ext_vector_type(4)));
typedef short s8v __attribute__((ext_vector_type(8)));
typedef float f4v __attribute__((ext_vector_type(4)));
typedef float f16v __attribute__((ext_vector_type(16)));
typedef int   i2v __attribute__((ext_vector_type(2)));

#define MF32(a,b,c) __builtin_amdgcn_mfma_f32_32x32x16_bf16(a,b,c,0,0,0)
#define MF16(a,b,c) __builtin_amdgcn_mfma_f32_16x16x32_bf16(a,b,c,0,0,0)
#define MFP32(a,b,c) __builtin_amdgcn_mfma_f32_32x32x16_fp8_fp8(a,b,c,0,0,0)
#define MFP16(a,b,c) __builtin_amdgcn_mfma_f32_16x16x32_fp8_fp8(a,b,c,0,0,0)

#if __has_builtin(__builtin_amdgcn_exp2f)
#define E2(x) __builtin_amdgcn_exp2f(x)
#else
#define E2(x) exp2f(x)
#endif

__device__ __forceinline__ uint16_t f2bf(float f){ union{float f;uint32_t i;}t; t.f=f; return (uint16_t)((t.i + 0x7fffu + ((t.i>>16)&1u))>>16); }
__device__ __forceinline__ float bf2f(uint16_t h){ union{uint32_t i;float f;}t; t.i=((uint32_t)h)<<16; return t.f; }
__device__ __forceinline__ float bfLO(uint32_t u){ union{uint32_t i;float f;}t; t.i=u<<16; return t.f; }
__device__ __forceinline__ float bfHI(uint32_t u){ union{uint32_t i;float f;}t; t.i=u&0xffff0000u; return t.f; }
__device__ __forceinline__ uint32_t cvtpk(float lo, float hi){ uint32_t r; asm("v_cvt_pk_bf16_f32 %0, %1, %2" : "=v"(r) : "v"(lo), "v"(hi)); return r; }
__device__ __forceinline__ void pl32swap(uint32_t &x, uint32_t &y){
#if __has_builtin(__builtin_amdgcn_permlane32_swap)
  i2v rr = __builtin_amdgcn_permlane32_swap((int)x, (int)y, false, false);
  x = (uint32_t)rr.x; y = (uint32_t)rr.y;
#else
  asm("v_permlane32_swap_b32 %0, %1" : "+v"(x), "+v"(y));
#endif
}
__device__ __forceinline__ float ftanh(float x){ float t = E2(2.885390081777927f*x); return __builtin_fmaf(-2.f, __builtin_amdgcn_rcpf(1.f + t), 1.f); }
__device__ __forceinline__ s8v ld8(const uint16_t* p){ return *(const s8v*)p; }

__device__ __forceinline__ uint32_t sw1fp8(float f){
  union{float f;uint32_t u;}t; t.f=f;
  uint32_t sgn=(t.u>>24)&0x80u; uint32_t a=t.u&0x7fffffffu;
  union{uint32_t u;float f;}af; af.u=a;
  if(af.f>448.f) return sgn|0x7eu;
  if(af.f<0.001953125f){ int q=(int)(af.f*512.f+0.5f); if(q>7)q=7; return sgn|(uint32_t)q; }
  uint32_t lsb=(a>>20)&1u; a+=0x0007ffffu+lsb;
  int ex=(int)(a>>23)-120; uint32_t man=(a>>20)&7u;
  if(ex>15||(ex==15&&man==7u)) return sgn|0x7eu;
  if(ex<=0){ int q=(int)(af.f*512.f+0.5f); if(q>7)q=7; return sgn|(uint32_t)q; }
  return sgn|((uint32_t)ex<<3)|man;
}
__device__ __forceinline__ uint32_t pk4fp8(float a,float b,float c,float d){
#if __has_builtin(__builtin_amdgcn_cvt_pk_fp8_f32)
  int v = __builtin_amdgcn_cvt_pk_fp8_f32(a,b,0,false);
  v = __builtin_amdgcn_cvt_pk_fp8_f32(c,d,v,true);
  return (uint32_t)v;
#else
  return sw1fp8(a) | (sw1fp8(b)<<8) | (sw1fp8(c)<<16) | (sw1fp8(d)<<24);
#endif
}
__device__ __forceinline__ s8v packw8(float4 f0, float4 f1){
  union{uint32_t d[4]; s8v v8;} A;
  A.d[0]=cvtpk(f0.x,f0.y); A.d[1]=cvtpk(f0.z,f0.w);
  A.d[2]=cvtpk(f1.x,f1.y); A.d[3]=cvtpk(f1.z,f1.w);
  return A.v8;
}

#define ROWF(e2) (((e2)&3) + 8*((e2)>>2) + 4*h2)
#define VXA(row,off) ((((row)<<5) + (off)) ^ (((row)&7)<<3))
#define VX8(row,b) ((((row)<<5) + (b)) ^ (((row)&3)<<4))

// staging buffer for output transpose
__device__ __align__(16) float gStage[32*12*12800];

// ---- S map: 39,712 u16 = 79,424 B  (2 blocks/CU: 2x79.8KB <= 160KB) ----
#define X1B 0
#define X2B 12800
#define XCV 12800
#define GCV 25856
#define XTU 25856
#define RINV 38912
#define CINV 39312
#define HV 0
#define F2V 12800

__global__ __launch_bounds__(TT, 4) void dymix(
    const float* __restrict__ x,
    const float* __restrict__ w1, const float* __restrict__ b1,
    const float* __restrict__ w2, const float* __restrict__ b2,
    const float* __restrict__ wm1, const float* __restrict__ bm1,
    const float* __restrict__ wm2, const float* __restrict__ bm2)
{
  __shared__ __align__(16) uint16_t S[39712];
  uint8_t* S8 = (uint8_t*)S;

  const int blk = blockIdx.x;
  const int xcd = blk & 7, slot = blk >> 3;
  const int n = xcd*4 + slot/12;
  const int l = slot - (slot/12)*12;
  const int t = threadIdx.x;
  const int wv = t >> 6;        // 0..7
  const int lane = t & 63;
  const int q  = lane >> 4;
  const int r  = lane & 15;
  const int h2 = lane >> 5;
  const int m32 = lane & 31;
  const long xbase = (long)n*153600 + l;

  // ---------- Phase 0: stage X -> XCV [c][408] ----------
  for (int i = t; i < 12800; i += TT) {
    int c = i / 400, v = i - c*400;
    S[XCV + c*STRD + v] = f2bf(x[xbase + (long)i*12]);
  }
  __syncthreads();

  // ---------- XT (swizzled [v][32] bf16) into GCV region ----------
  for (int i = t; i < 12800; i += TT) { int v = i>>5, c = i&31; S[XTU + VXA(v,c)] = S[XCV + c*STRD + v]; }
  __syncthreads();

  // ---------- Phase L: x1 = log2e*tanh(W1 X + b1) fp8, x2 = tanh(W2 X + b2) fp8.
  // 28 units over 8 waves x 4 jj slots. Weights/biases from GLOBAL (no LDS staging). ----------
  #pragma unroll
  for (int j = 0; j < 4; ++j) {
    int u = wv + 8*j;
    if (u < 24) {
      int nt = u >> 1, li = u & 1;
      const float* wsrc = li ? w2 : w1;
      const float* bsrc = li ? b2 : b1;
      uint8_t* dst8 = S8 + (li ? X2B : X1B);
      const float osc = li ? 1.f : LOG2E;
      f16v z = {};
      #pragma unroll
      for (int kk = 0; kk < 2; ++kk) {
        const float* wp = wsrc + m32*32 + kk*16 + h2*8;
        s8v a = packw8(*(const float4*)(wp), *(const float4*)(wp+4));
        s8v b = ld8(S + XTU + VXA(nt*32 + m32, kk*16 + h2*8));
        z = MF32(a, b, z);
      }
      int v = nt*32 + m32;
      #pragma unroll
      for (int g = 0; g < 4; ++g) {
        float4 bv = *(const float4*)(bsrc + 8*g + 4*h2);
        float p0 = ftanh(z[4*g+0] + bv.x) * osc;
        float p1 = ftanh(z[4*g+1] + bv.y) * osc;
        float p2 = ftanh(z[4*g+2] + bv.z) * osc;
        float p3 = ftanh(z[4*g+3] + bv.w) * osc;
        *(uint32_t*)(dst8 + VX8(v, 8*g + 4*h2)) = pk4fp8(p0,p1,p2,p3);
      }
    } else if (u < 28) {
      int li = (u-24)>>1, mt = u&1;
      const float* wsrc = li ? w2 : w1;
      const float* bsrc = li ? b2 : b1;
      uint8_t* dst8 = S8 + (li ? X2B : X1B);
      const float osc = li ? 1.f : LOG2E;
      const float* wp = wsrc + (mt*16 + r)*32 + q*8;
      s8v a = packw8(*(const float4*)(wp), *(const float4*)(wp+4));
      s8v b = ld8(S + XTU + VXA(384 + r, q*8));
      f4v z4 = {}; z4 = MF16(a, b, z4);
      float4 bv = *(const float4*)(bsrc + mt*16 + q*4);
      float p0 = ftanh(z4[0] + bv.x) * osc;
      float p1 = ftanh(z4[1] + bv.y) * osc;
      float p2 = ftanh(z4[2] + bv.z) * osc;
      float p3 = ftanh(z4[3] + bv.w) * osc;
      *(uint32_t*)(dst8 + VX8(384 + r, mt*16 + q*4)) = pk4fp8(p0,p1,p2,p3);
    }
  }
  // preload MLP X b-frags (bf16) from XT before stats overwrites it.
  // MLP m-units per wave: m = wv (always main) and m = wv+8 (main if wv<4, tail if wv in {4,5}).
  s8v xf0a, xf1a, xf0b, xf1b, xft;
  {
    xf0a = ld8(S + XTU + VXA(wv*32 + m32, h2*8));
    xf1a = ld8(S + XTU + VXA(wv*32 + m32, 16 + h2*8));
    int mb = (wv < 4) ? (wv + 8) : 0;
    xf0b = ld8(S + XTU + VXA(mb*32 + m32, h2*8));
    xf1b = ld8(S + XTU + VXA(mb*32 + m32, 16 + h2*8));
    xft  = ld8(S + XTU + VXA(384 + r, q*8));
  }
  __syncthreads();

  // ---------- Stats: rowsum/colsum of exp2(A') — fp8 QK^T (25 v-tiles over 8 waves x 4 jj) ----------
  float* rsf = (float*)(S + GCV);
  float* csf = rsf + 400;
  for (int i = t; i < 400; i += TT) csf[i] = 0.f;
  __syncthreads();
  {
    long av8[4]; f4v rac[4] = {{},{},{},{}};
    #pragma unroll
    for (int jj = 0; jj < 4; ++jj) { int vt = wv + 8*jj; if (vt < 25) av8[jj] = *(const long*)(S8 + X1B + VX8(vt*16 + r, q*8)); }
    for (int wt = 0; wt < 25; ++wt) {
      long b8 = *(const long*)(S8 + X2B + VX8(wt*16 + r, q*8));
      float cp = 0.f;
      #pragma unroll
      for (int jj = 0; jj < 4; ++jj) {
        int vt = wv + 8*jj;
        if (vt < 25) {
          f4v z = {}; z = MFP16(av8[jj], b8, z);
          #pragma unroll
          for (int e = 0; e < 4; ++e) { float ev = E2(z[e]); rac[jj][e] += ev; cp += ev; }
        }
      }
      cp += __shfl_xor(cp, 16); cp += __shfl_xor(cp, 32);
      if (q == 0) atomicAdd(&csf[wt*16 + r], cp);
    }
    #pragma unroll
    for (int jj = 0; jj < 4; ++jj) {
      int vt = wv + 8*jj;
      if (vt < 25) {
        #pragma unroll
        for (int e = 0; e < 4; ++e) {
          float s = rac[jj][e];
          s += __shfl_xor(s,1); s += __shfl_xor(s,2); s += __shfl_xor(s,4); s += __shfl_xor(s,8);
          if (r == 0) rsf[vt*16 + q*4 + e] = s;
        }
      }
    }
  }
  __syncthreads();
  for (int i = t; i < 400; i += TT) { S[RINV + i] = f2bf(1.f/rsf[i]); S[CINV + i] = f2bf(1.f/csf[i]); }
  __syncthreads();

  // ---------- Diffusion: 26 units over 8 waves x 4 jj, T+GEMM fused per unit
  // (register P everywhere; fp8 QK^T; H1 in place over X via split epilogue). ----------
  f16v acc[4];
  for (int step = 0; step < 2; ++step) {
    { f16v zv = {}; acc[0]=zv; acc[1]=zv; acc[2]=zv; acc[3]=zv; }
    const uint16_t* AH = S + XCV;                 // X (step0) / H1 (step1), same region
    const uint16_t* AG = S + (step ? GCV : XCV);
    for (int sb = 0; sb < 13; ++sb) {
      const int vbase = sb*32;
      const bool lastsb = (sb == 12);
      const int kmax = lastsb ? 1 : 2;
      #pragma unroll
      for (int jj = 0; jj < 4; ++jj) {
        int g = wv + 8*jj;
        if (g >= 26) continue;
        int chain = (g < 13) ? 0 : 1;
        int uu = g - 13*chain;
        const uint8_t* sa8 = S8 + (chain ? X2B : X1B);
        const uint8_t* sb8 = S8 + (chain ? X1B : X2B);
        const int scl = chain ? CINV : RINV;
        const uint16_t* Acv = chain ? AG : AH;
        if (uu < 12) {
          long a0 = *(const long*)(sa8 + VX8(vbase + m32, h2*8));
          long a1 = *(const long*)(sa8 + VX8(vbase + m32, 16 + h2*8));
          long b0 = *(const long*)(sb8 + VX8(uu*32 + m32, h2*8));
          long b1 = *(const long*)(sb8 + VX8(uu*32 + m32, 16 + h2*8));
          f16v z = {}; z = MFP32(a0, b0, z); z = MFP32(a1, b1, z);
          #pragma unroll
          for (int k = 0; k < 2; ++k) {
            if (k < kmax) {
              const uint16_t* spt = S + scl + vbase + 16*k + 4*h2;
              uint32_t sAB = *(const uint32_t*)(spt);
              uint32_t sCD = *(const uint32_t*)(spt + 2);
              uint32_t sEF = *(const uint32_t*)(spt + 8);
              uint32_t sGH = *(const uint32_t*)(spt + 10);
              uint32_t C0 = cvtpk(E2(z[8*k+0])*bfLO(sAB), E2(z[8*k+1])*bfHI(sAB));
              uint32_t C1 = cvtpk(E2(z[8*k+2])*bfLO(sCD), E2(z[8*k+3])*bfHI(sCD));
              uint32_t C2 = cvtpk(E2(z[8*k+4])*bfLO(sEF), E2(z[8*k+5])*bfHI(sEF));
              uint32_t C3 = cvtpk(E2(z[8*k+6])*bfLO(sGH), E2(z[8*k+7])*bfHI(sGH));
              pl32swap(C0, C2);
              pl32swap(C1, C3);
              union { uint32_t d[4]; s8v v8; } F;
              F.d[0] = C0; F.d[1] = C1; F.d[2] = C2; F.d[3] = C3;
              s8v a = ld8(Acv + m32*STRD + vbase + k*16 + h2*8);
              acc[jj] = MF32(a, F.v8, acc[jj]);
            }
          }
        } else {
          long bT = *(const long*)(sb8 + VX8(384 + r, q*8));
          uint2 td0, td1; td1.x = 0u; td1.y = 0u;
          {
            long a = *(const long*)(sa8 + VX8(vbase + r, q*8));
            f4v z4 = {}; z4 = MFP16(a, bT, z4);
            float p0 = E2(z4[0]) * bf2f(S[scl + vbase + q*4 + 0]);
            float p1 = E2(z4[1]) * bf2f(S[scl + vbase + q*4 + 1]);
            float p2 = E2(z4[2]) * bf2f(S[scl + vbase + q*4 + 2]);
            float p3 = E2(z4[3]) * bf2f(S[scl + vbase + q*4 + 3]);
            td0.x = cvtpk(p0,p1); td0.y = cvtpk(p2,p3);
          }
          if (!lastsb) {
            long a = *(const long*)(sa8 + VX8(vbase + 16 + r, q*8));
            f4v z4 = {}; z4 = MFP16(a, bT, z4);
            float p0 = E2(z4[0]) * bf2f(S[scl + vbase + 16 + q*4 + 0]);
            float p1 = E2(z4[1]) * bf2f(S[scl + vbase + 16 + q*4 + 1]);
            float p2 = E2(z4[2]) * bf2f(S[scl + vbase + 16 + q*4 + 2]);
            float p3 = E2(z4[3]) * bf2f(S[scl + vbase + 16 + q*4 + 3]);
            td1.x = cvtpk(p0,p1); td1.y = cvtpk(p2,p3);
          }
          const int src0 = (((q<<1)) & 3)*16 + r;
          const int src1 = (((q<<1)+1) & 3)*16 + r;
          uint32_t a0x = (uint32_t)__shfl((int)td0.x, src0);
          uint32_t a0y = (uint32_t)__shfl((int)td0.y, src0);
          uint32_t a1x = (uint32_t)__shfl((int)td1.x, src0);
          uint32_t a1y = (uint32_t)__shfl((int)td1.y, src0);
          uint32_t b0x = (uint32_t)__shfl((int)td0.x, src1);
          uint32_t b0y = (uint32_t)__shfl((int)td0.y, src1);
          uint32_t b1x = (uint32_t)__shfl((int)td1.x, src1);
          uint32_t b1y = (uint32_t)__shfl((int)td1.y, src1);
          const bool hi = (q >= 2);
          union { uint32_t u[4]; s8v v8; } B;
          B.u[0] = hi ? a1x : a0x;
          B.u[1] = hi ? a1y : a0y;
          B.u[2] = hi ? b1x : b0x;
          B.u[3] = hi ? b1y : b0y;
          #pragma unroll
          for (int mt2 = 0; mt2 < 2; ++mt2) {
            int koff = (lastsb && q >= 2) ? 0 : q*8;
            s8v a = ld8(Acv + (mt2*16 + r)*STRD + vbase + koff);
            f4v c4 = { acc[jj][4*mt2+0], acc[jj][4*mt2+1], acc[jj][4*mt2+2], acc[jj][4*mt2+3] };
            c4 = MF16(a, B.v8, c4);
            acc[jj][4*mt2+0]=c4[0]; acc[jj][4*mt2+1]=c4[1]; acc[jj][4*mt2+2]=c4[2]; acc[jj][4*mt2+3]=c4[3];
          }
        }
      }
    } // sb
    __syncthreads();
    if (step == 0) {
      // epilogue phase i (reads only): acc = AL*X + OM*acc
      #pragma unroll
      for (int jj = 0; jj < 4; ++jj) {
        int g = wv + 8*jj;
        if (g >= 26) continue;
        int chain = (g < 13) ? 0 : 1;
        int uu = g - 13*chain;
        if (uu < 12) {
          int w = uu*32 + m32;
          #pragma unroll
          for (int e2 = 0; e2 < 16; ++e2) {
            int c = ROWF(e2);
            acc[jj][e2] = AL*bf2f(S[XCV + c*STRD + w]) + OM*acc[jj][e2];
          }
        } else {
          int w = 384 + r;
          #pragma unroll
          for (int mt2 = 0; mt2 < 2; ++mt2)
            #pragma unroll
            for (int e = 0; e < 4; ++e) {
              int c = mt2*16 + q*4 + e;
              acc[jj][4*mt2+e] = AL*bf2f(S[XCV + c*STRD + w]) + OM*acc[jj][4*mt2+e];
            }
        }
      }
      __syncthreads();
      // epilogue phase ii (writes): H1 -> XCV (in place), G1 -> GCV
      #pragma unroll
      for (int jj = 0; jj < 4; ++jj) {
        int g = wv + 8*jj;
        if (g >= 26) continue;
        int chain = (g < 13) ? 0 : 1;
        int uu = g - 13*chain;
        uint16_t* dst = S + (chain ? GCV : XCV);
        if (uu < 12) {
          int w = uu*32 + m32;
          #pragma unroll
          for (int e2 = 0; e2 < 16; ++e2) { int c = ROWF(e2); dst[c*STRD + w] = f2bf(acc[jj][e2]); }
        } else {
          int w = 384 + r;
          #pragma unroll
          for (int mt2 = 0; mt2 < 2; ++mt2)
            #pragma unroll
            for (int e = 0; e < 4; ++e) { int c = mt2*16 + q*4 + e; dst[c*STRD + w] = f2bf(acc[jj][4*mt2+e]); }
        }
      }
      __syncthreads();
    }
  } // step

  // ---------- MLP: two passes (chain0 -> gStage write; chain1 -> add). Weights from global. ----------
  // PREP A: H1 [c][408] -> Hv [v][32] bf16 (over dead fp8 x1/x2)
  for (int i = t; i < 12800; i += TT) { int v = i >> 5, c = i & 31; S[HV + VXA(v,c)] = S[XCV + c*STRD + v]; }
  __syncthreads();
  // H2'v = OM*acc (chain-0 units) -> F2V (over XCV region)
  #pragma unroll
  for (int jj = 0; jj < 4; ++jj) {
    int g = wv + 8*jj;
    if (g >= 13) continue;              // chain 0 only
    int uu = g;
    uint16_t* dst = S + F2V;
    if (uu < 12) {
      int w = uu*32 + m32;
      #pragma unroll
      for (int gg = 0; gg < 4; ++gg) {
        uint2 d;
        d.x = cvtpk(OM*acc[jj][4*gg+0], OM*acc[jj][4*gg+1]);
        d.y = cvtpk(OM*acc[jj][4*gg+2], OM*acc[jj][4*gg+3]);
        *(uint2*)(dst + VXA(w, 8*gg + 4*h2)) = d;
      }
    } else {
      int w = 384 + r;
      #pragma unroll
      for (int mt2 = 0; mt2 < 2; ++mt2) {
        uint2 d;
        d.x = cvtpk(OM*acc[jj][4*mt2+0], OM*acc[jj][4*mt2+1]);
        d.y = cvtpk(OM*acc[jj][4*mt2+2], OM*acc[jj][4*mt2+3]);
        *(uint2*)(dst + VXA(w, mt2*16 + q*4)) = d;
      }
    }
  }
  __syncthreads();

  float* oSl = gStage + (long)(n*12 + l)*12800;
  // ---- PASS A (wm1, + combined bias): m-units m = wv + 8*jm ----
  #pragma unroll
  for (int jm = 0; jm < 2; ++jm) {
    int m = wv + 8*jm;
    if (m < 12) {
      f16v z = {};
      #pragma unroll
      for (int p = 0; p < 3; ++p) {
        #pragma unroll
        for (int kk = 0; kk < 2; ++kk) {
          const float* wp = wm1 + m32*96 + p*32 + kk*16 + h2*8;
          float4 f0 = *(const float4*)(wp), f1 = *(const float4*)(wp+4);
          if (p == 0) {
            const float* wp2 = wm1 + m32*96 + 64 + kk*16 + h2*8;
            float4 g0 = *(const float4*)(wp2), g1 = *(const float4*)(wp2+4);
            f0.x += AL*g0.x; f0.y += AL*g0.y; f0.z += AL*g0.z; f0.w += AL*g0.w;
            f1.x += AL*g1.x; f1.y += AL*g1.y; f1.z += AL*g1.z; f1.w += AL*g1.w;
          }
          s8v a = packw8(f0, f1);
          s8v b;
          if (p == 0) b = jm ? (kk ? xf1b : xf0b) : (kk ? xf1a : xf0a);
          else        b = ld8(S + (p == 1 ? HV : F2V) + VXA(m*32 + m32, kk*16 + h2*8));
          z = MF32(a, b, z);
        }
      }
      int v = m*32 + m32;
      #pragma unroll
      for (int e2 = 0; e2 < 16; ++e2) { int o = ROWF(e2); oSl[o*400 + v] = z[e2] + bm1[o] + bm2[o]; }
    } else if (m < 14) {
      int mt = m - 12;
      f4v z4 = {};
      #pragma unroll
      for (int p = 0; p < 3; ++p) {
        const float* wp = wm1 + (mt*16 + r)*96 + p*32 + q*8;
        float4 f0 = *(const float4*)(wp), f1 = *(const float4*)(wp+4);
        if (p == 0) {
          const float* wp2 = wm1 + (mt*16 + r)*96 + 64 + q*8;
          float4 g0 = *(const float4*)(wp2), g1 = *(const float4*)(wp2+4);
          f0.x += AL*g0.x; f0.y += AL*g0.y; f0.z += AL*g0.z; f0.w += AL*g0.w;
          f1.x += AL*g1.x; f1.y += AL*g1.y; f1.z += AL*g1.z; f1.w += AL*g1.w;
        }
        s8v a = packw8(f0, f1);
        s8v b = (p == 0) ? xft : ld8(S + (p == 1 ? HV : F2V) + VXA(384 + r, q*8));
        z4 = MF16(a, b, z4);
      }
      #pragma unroll
      for (int e = 0; e < 4; ++e) { int o = mt*16 + q*4 + e; oSl[o*400 + 384 + r] = z4[e] + bm1[o] + bm2[o]; }
    }
  }
  __syncthreads();
  // ---- PREP B: G1 -> Hv ; G2'v (chain-1 units) -> F2V ----
  for (int i = t; i < 12800; i += TT) { int v = i >> 5, c = i & 31; S[HV + VXA(v,c)] = S[GCV + c*STRD + v]; }
  #pragma unroll
  for (int jj = 0; jj < 4; ++jj) {
    int g = wv + 8*jj;
    if (g < 13 || g >= 26) continue;    // chain 1 only
    int uu = g - 13;
    uint16_t* dst = S + F2V;
    if (uu < 12) {
      int w = uu*32 + m32;
      #pragma unroll
      for (int gg = 0; gg < 4; ++gg) {
        uint2 d;
        d.x = cvtpk(OM*acc[jj][4*gg+0], OM*acc[jj][4*gg+1]);
        d.y = cvtpk(OM*acc[jj][4*gg+2], OM*acc[jj][4*gg+3]);
        *(uint2*)(dst + VXA(w, 8*gg + 4*h2)) = d;
      }
    } else {
      int w = 384 + r;
      #pragma unroll
      for (int mt2 = 0; mt2 < 2; ++mt2) {
        uint2 d;
        d.x = cvtpk(OM*acc[jj][4*mt2+0], OM*acc[jj][4*mt2+1]);
        d.y = cvtpk(OM*acc[jj][4*mt2+2], OM*acc[jj][4*mt2+3]);
        *(uint2*)(dst + VXA(w, mt2*16 + q*4)) = d;
      }
    }
  }
  __syncthreads();
  // ---- PASS B (wm2, accumulate into gStage) ----
  #pragma unroll
  for (int jm = 0; jm < 2; ++jm) {
    int m = wv + 8*jm;
    if (m < 12) {
      f16v z = {};
      #pragma unroll
      for (int p = 0; p < 3; ++p) {
        #pragma unroll
        for (int kk = 0; kk < 2; ++kk) {
          const float* wp = wm2 + m32*96 + p*32 + kk*16 + h2*8;
          float4 f0 = *(const float4*)(wp), f1 = *(const float4*)(wp+4);
          if (p == 0) {
            const float* wp2 = wm2 + m32*96 + 64 + kk*16 + h2*8;
            float4 g0 = *(const float4*)(wp2), g1 = *(const float4*)(wp2+4);
            f0.x += AL*g0.x; f0.y += AL*g0.y; f0.z += AL*g0.z; f0.w += AL*g0.w;
            f1.x += AL*g1.x; f1.y += AL*g1.y; f1.z += AL*g1.z; f1.w += AL*g1.w;
          }
          s8v a = packw8(f0, f1);
          s8v b;
          if (p == 0) b = jm ? (kk ? xf1b : xf0b) : (kk ? xf1a : xf0a);
          else        b = ld8(S + (p == 1 ? HV : F2V) + VXA(m*32 + m32, kk*16 + h2*8));
          z = MF32(a, b, z);
        }
      }
      int v = m*32 + m32;
      #pragma unroll
      for (int e2 = 0; e2 < 16; ++e2) { int o = ROWF(e2); oSl[o*400 + v] += z[e2]; }
    } else if (m < 14) {
      int mt = m - 12;
      f4v z4 = {};
      #pragma unroll
      for (int p = 0; p < 3; ++p) {
        const float* wp = wm2 + (mt*16 + r)*96 + p*32 + q*8;
        float4 f0 = *(const float4*)(wp), f1 = *(const float4*)(wp+4);
        if (p == 0) {
          const float* wp2 = wm2 + (mt*16 + r)*96 + 64 + q*8;
          float4 g0 = *(const float4*)(wp2), g1 = *(const float4*)(wp2+4);
          f0.x += AL*g0.x; f0.y += AL*g0.y; f0.z += AL*g0.z; f0.w += AL*g0.w;
          f1.x += AL*g1.x; f1.y += AL*g1.y; f1.z += AL*g1.z; f1.w += AL*g1.w;
        }
        s8v a = packw8(f0, f1);
        s8v b = (p == 0) ? xft : ld8(S + (p == 1 ? HV : F2V) + VXA(384 + r, q*8));
        z4 = MF16(a, b, z4);
      }
      #pragma unroll
      for (int e = 0; e < 4; ++e) { int o = mt*16 + q*4 + e; oSl[o*400 + 384 + r] += z4[e]; }
    }
  }
}

// Plain transpose kernel: gStage[n][l][o][v] -> out[n][o][v][l] (both sides coalesced)
__global__ __launch_bounds__(256) void finT(float* __restrict__ out) {
  int idx = blockIdx.x*256 + threadIdx.x;
  int n = idx / 12800, ov = idx - n*12800;
  const float* src = gStage + (long)n*153600 + ov;
  float vals[12];
  #pragma unroll
  for (int l = 0; l < 12; ++l) vals[l] = src[(long)l*12800];
  float4* dst = (float4*)(out + (long)idx*12);
  dst[0] = make_float4(vals[0],vals[1],vals[2],vals[3]);
  dst[1] = make_float4(vals[4],vals[5],vals[6],vals[7]);
  dst[2] = make_float4(vals[8],vals[9],vals[10],vals[11]);
}

extern "C" void kernel_launch(void* const* d_in, const int* in_sizes, int n_in,
                              void* d_out, int out_size, void* d_ws, size_t ws_size,
                              hipStream_t stream) {
  (void)in_sizes; (void)n_in; (void)out_size; (void)d_ws; (void)ws_size;
  dymix<<<dim3(384), dim3(TT), 0, stream>>>(
      (const float*)d_in[0],
      (const float*)d_in[1], (const float*)d_in[2],
      (const float*)d_in[3], (const float*)d_in[4],
      (const float*)d_in[5], (const float*)d_in[6],
      (const float*)d_in[7], (const float*)d_in[8]);
  finT<<<dim3(1600), dim3(256), 0, stream>>>((float*)d_out);
}

// Round 9
// 216.567 us; speedup vs baseline: 1.1738x; 1.0115x over previous
//
#include <hip/hip_runtime.h>
#include <stdint.h>

#define TT 512
#define AL 0.05f
#define OM 0.95f
#define STRD 408   // padded [c][.] row stride
#define LOG2E 1.4426950408889634f

typedef short s4v __attribute__((ext_vector_type(4)));
typedef short s8v __attribute__((ext_vector_type(8)));
typedef float f4v __attribute__((ext_vector_type(4)));
typedef float f16v __attribute__((ext_vector_type(16)));
typedef int   i2v __attribute__((ext_vector_type(2)));

#define MF32(a,b,c) __builtin_amdgcn_mfma_f32_32x32x16_bf16(a,b,c,0,0,0)
#define MF16(a,b,c) __builtin_amdgcn_mfma_f32_16x16x32_bf16(a,b,c,0,0,0)
#define MFP32(a,b,c) __builtin_amdgcn_mfma_f32_32x32x16_fp8_fp8(a,b,c,0,0,0)
#define MFP16(a,b,c) __builtin_amdgcn_mfma_f32_16x16x32_fp8_fp8(a,b,c,0,0,0)

#if __has_builtin(__builtin_amdgcn_exp2f)
#define E2(x) __builtin_amdgcn_exp2f(x)
#else
#define E2(x) exp2f(x)
#endif

__device__ __forceinline__ uint16_t f2bf(float f){ union{float f;uint32_t i;}t; t.f=f; return (uint16_t)((t.i + 0x7fffu + ((t.i>>16)&1u))>>16); }
__device__ __forceinline__ float bf2f(uint16_t h){ union{uint32_t i;float f;}t; t.i=((uint32_t)h)<<16; return t.f; }
__device__ __forceinline__ float bfLO(uint32_t u){ union{uint32_t i;float f;}t; t.i=u<<16; return t.f; }
__device__ __forceinline__ float bfHI(uint32_t u){ union{uint32_t i;float f;}t; t.i=u&0xffff0000u; return t.f; }
__device__ __forceinline__ uint32_t cvtpk(float lo, float hi){ uint32_t r; asm("v_cvt_pk_bf16_f32 %0, %1, %2" : "=v"(r) : "v"(lo), "v"(hi)); return r; }
__device__ __forceinline__ void pl32swap(uint32_t &x, uint32_t &y){
#if __has_builtin(__builtin_amdgcn_permlane32_swap)
  i2v rr = __builtin_amdgcn_permlane32_swap((int)x, (int)y, false, false);
  x = (uint32_t)rr.x; y = (uint32_t)rr.y;
#else
  asm("v_permlane32_swap_b32 %0, %1" : "+v"(x), "+v"(y));
#endif
}
__device__ __forceinline__ float ftanh(float x){ float t = E2(2.885390081777927f*x); return __builtin_fmaf(-2.f, __builtin_amdgcn_rcpf(1.f + t), 1.f); }
__device__ __forceinline__ s8v ld8(const uint16_t* p){ return *(const s8v*)p; }

__device__ __forceinline__ uint32_t sw1fp8(float f){
  union{float f;uint32_t u;}t; t.f=f;
  uint32_t sgn=(t.u>>24)&0x80u; uint32_t a=t.u&0x7fffffffu;
  union{uint32_t u;float f;}af; af.u=a;
  if(af.f>448.f) return sgn|0x7eu;
  if(af.f<0.001953125f){ int q=(int)(af.f*512.f+0.5f); if(q>7)q=7; return sgn|(uint32_t)q; }
  uint32_t lsb=(a>>20)&1u; a+=0x0007ffffu+lsb;
  int ex=(int)(a>>23)-120; uint32_t man=(a>>20)&7u;
  if(ex>15||(ex==15&&man==7u)) return sgn|0x7eu;
  if(ex<=0){ int q=(int)(af.f*512.f+0.5f); if(q>7)q=7; return sgn|(uint32_t)q; }
  return sgn|((uint32_t)ex<<3)|man;
}
__device__ __forceinline__ uint32_t pk4fp8(float a,float b,float c,float d){
#if __has_builtin(__builtin_amdgcn_cvt_pk_fp8_f32)
  int v = __builtin_amdgcn_cvt_pk_fp8_f32(a,b,0,false);
  v = __builtin_amdgcn_cvt_pk_fp8_f32(c,d,v,true);
  return (uint32_t)v;
#else
  return sw1fp8(a) | (sw1fp8(b)<<8) | (sw1fp8(c)<<16) | (sw1fp8(d)<<24);
#endif
}
__device__ __forceinline__ s8v packw8(float4 f0, float4 f1){
  union{uint32_t d[4]; s8v v8;} A;
  A.d[0]=cvtpk(f0.x,f0.y); A.d[1]=cvtpk(f0.z,f0.w);
  A.d[2]=cvtpk(f1.x,f1.y); A.d[3]=cvtpk(f1.z,f1.w);
  return A.v8;
}

#define ROWF(e2) (((e2)&3) + 8*((e2)>>2) + 4*h2)
#define VXA(row,off) ((((row)<<5) + (off)) ^ (((row)&7)<<3))
// fp8 [v][32B] swizzle, FIXED (r9): bank = 8*(row&3) + 2*(slot ^ (row>>2)&3).
// Old (row&3)<<4 collided with the 8*row bank base -> 8-way on diffusion T loads;
// XOR with (row>>2)&3 gives 16 distinct bank positions, 2 lanes each = free.
#define VX8(row,b) ((((row)<<5) + (b)) ^ ((((row)>>2)&3)<<3))

// staging buffer for output transpose
__device__ __align__(16) float gStage[32*12*12800];

// ---- S map: 39,712 u16 = 79,424 B  (2 blocks/CU: 2x79.8KB <= 160KB) ----
#define X1B 0
#define X2B 12800
#define XCV 12800
#define GCV 25856
#define XTU 25856
#define RINV 38912
#define CINV 39312
#define HV 0
#define F2V 12800

__global__ __launch_bounds__(TT, 4) void dymix(
    const float* __restrict__ x,
    const float* __restrict__ w1, const float* __restrict__ b1,
    const float* __restrict__ w2, const float* __restrict__ b2,
    const float* __restrict__ wm1, const float* __restrict__ bm1,
    const float* __restrict__ wm2, const float* __restrict__ bm2)
{
  __shared__ __align__(16) uint16_t S[39712];
  uint8_t* S8 = (uint8_t*)S;

  const int blk = blockIdx.x;
  const int xcd = blk & 7, slot = blk >> 3;
  const int n = xcd*4 + slot/12;
  const int l = slot - (slot/12)*12;
  const int t = threadIdx.x;
  const int wv = t >> 6;        // 0..7
  const int lane = t & 63;
  const int q  = lane >> 4;
  const int r  = lane & 15;
  const int h2 = lane >> 5;
  const int m32 = lane & 31;
  const long xbase = (long)n*153600 + l;

  // ---------- Phase 0: stage X -> XCV [c][408] ----------
  for (int i = t; i < 12800; i += TT) {
    int c = i / 400, v = i - c*400;
    S[XCV + c*STRD + v] = f2bf(x[xbase + (long)i*12]);
  }
  __syncthreads();

  // ---------- XT (swizzled [v][32] bf16) into GCV region ----------
  for (int i = t; i < 12800; i += TT) { int v = i>>5, c = i&31; S[XTU + VXA(v,c)] = S[XCV + c*STRD + v]; }
  __syncthreads();

  // ---------- Phase L: x1 = log2e*tanh(W1 X + b1) fp8, x2 = tanh(W2 X + b2) fp8.
  // 28 units over 8 waves x 4 jj slots. Weights/biases from GLOBAL (no LDS staging). ----------
  #pragma unroll
  for (int j = 0; j < 4; ++j) {
    int u = wv + 8*j;
    if (u < 24) {
      int nt = u >> 1, li = u & 1;
      const float* wsrc = li ? w2 : w1;
      const float* bsrc = li ? b2 : b1;
      uint8_t* dst8 = S8 + (li ? X2B : X1B);
      const float osc = li ? 1.f : LOG2E;
      f16v z = {};
      #pragma unroll
      for (int kk = 0; kk < 2; ++kk) {
        const float* wp = wsrc + m32*32 + kk*16 + h2*8;
        s8v a = packw8(*(const float4*)(wp), *(const float4*)(wp+4));
        s8v b = ld8(S + XTU + VXA(nt*32 + m32, kk*16 + h2*8));
        z = MF32(a, b, z);
      }
      int v = nt*32 + m32;
      #pragma unroll
      for (int g = 0; g < 4; ++g) {
        float4 bv = *(const float4*)(bsrc + 8*g + 4*h2);
        float p0 = ftanh(z[4*g+0] + bv.x) * osc;
        float p1 = ftanh(z[4*g+1] + bv.y) * osc;
        float p2 = ftanh(z[4*g+2] + bv.z) * osc;
        float p3 = ftanh(z[4*g+3] + bv.w) * osc;
        *(uint32_t*)(dst8 + VX8(v, 8*g + 4*h2)) = pk4fp8(p0,p1,p2,p3);
      }
    } else if (u < 28) {
      int li = (u-24)>>1, mt = u&1;
      const float* wsrc = li ? w2 : w1;
      const float* bsrc = li ? b2 : b1;
      uint8_t* dst8 = S8 + (li ? X2B : X1B);
      const float osc = li ? 1.f : LOG2E;
      const float* wp = wsrc + (mt*16 + r)*32 + q*8;
      s8v a = packw8(*(const float4*)(wp), *(const float4*)(wp+4));
      s8v b = ld8(S + XTU + VXA(384 + r, q*8));
      f4v z4 = {}; z4 = MF16(a, b, z4);
      float4 bv = *(const float4*)(bsrc + mt*16 + q*4);
      float p0 = ftanh(z4[0] + bv.x) * osc;
      float p1 = ftanh(z4[1] + bv.y) * osc;
      float p2 = ftanh(z4[2] + bv.z) * osc;
      float p3 = ftanh(z4[3] + bv.w) * osc;
      *(uint32_t*)(dst8 + VX8(384 + r, mt*16 + q*4)) = pk4fp8(p0,p1,p2,p3);
    }
  }
  // preload MLP X b-frags (bf16) from XT before stats overwrites it.
  s8v xf0a, xf1a, xf0b, xf1b, xft;
  {
    xf0a = ld8(S + XTU + VXA(wv*32 + m32, h2*8));
    xf1a = ld8(S + XTU + VXA(wv*32 + m32, 16 + h2*8));
    int mb = (wv < 4) ? (wv + 8) : 0;
    xf0b = ld8(S + XTU + VXA(mb*32 + m32, h2*8));
    xf1b = ld8(S + XTU + VXA(mb*32 + m32, 16 + h2*8));
    xft  = ld8(S + XTU + VXA(384 + r, q*8));
  }
  __syncthreads();

  // ---------- Stats: rowsum/colsum of exp2(A') — fp8 QK^T (25 v-tiles over 8 waves x 4 jj) ----------
  float* rsf = (float*)(S + GCV);
  float* csf = rsf + 400;
  for (int i = t; i < 400; i += TT) csf[i] = 0.f;
  __syncthreads();
  {
    long av8[4]; f4v rac[4] = {{},{},{},{}};
    #pragma unroll
    for (int jj = 0; jj < 4; ++jj) { int vt = wv + 8*jj; if (vt < 25) av8[jj] = *(const long*)(S8 + X1B + VX8(vt*16 + r, q*8)); }
    for (int wt = 0; wt < 25; ++wt) {
      long b8 = *(const long*)(S8 + X2B + VX8(wt*16 + r, q*8));
      float cp = 0.f;
      #pragma unroll
      for (int jj = 0; jj < 4; ++jj) {
        int vt = wv + 8*jj;
        if (vt < 25) {
          f4v z = {}; z = MFP16(av8[jj], b8, z);
          #pragma unroll
          for (int e = 0; e < 4; ++e) { float ev = E2(z[e]); rac[jj][e] += ev; cp += ev; }
        }
      }
      cp += __shfl_xor(cp, 16); cp += __shfl_xor(cp, 32);
      if (q == 0) atomicAdd(&csf[wt*16 + r], cp);
    }
    #pragma unroll
    for (int jj = 0; jj < 4; ++jj) {
      int vt = wv + 8*jj;
      if (vt < 25) {
        #pragma unroll
        for (int e = 0; e < 4; ++e) {
          float s = rac[jj][e];
          s += __shfl_xor(s,1); s += __shfl_xor(s,2); s += __shfl_xor(s,4); s += __shfl_xor(s,8);
          if (r == 0) rsf[vt*16 + q*4 + e] = s;
        }
      }
    }
  }
  __syncthreads();
  for (int i = t; i < 400; i += TT) { S[RINV + i] = f2bf(1.f/rsf[i]); S[CINV + i] = f2bf(1.f/csf[i]); }
  __syncthreads();

  // ---------- Diffusion: 26 units over 8 waves x 4 jj, T+GEMM fused per unit
  // (register P everywhere; fp8 QK^T; H1 in place over X via split epilogue).
  // r9: setprio(1) around the sb body — 2-3 desynced blocks/CU is the regime where it pays. ----------
  f16v acc[4];
  for (int step = 0; step < 2; ++step) {
    { f16v zv = {}; acc[0]=zv; acc[1]=zv; acc[2]=zv; acc[3]=zv; }
    const uint16_t* AH = S + XCV;                 // X (step0) / H1 (step1), same region
    const uint16_t* AG = S + (step ? GCV : XCV);
    for (int sb = 0; sb < 13; ++sb) {
      const int vbase = sb*32;
      const bool lastsb = (sb == 12);
      const int kmax = lastsb ? 1 : 2;
      __builtin_amdgcn_s_setprio(1);
      #pragma unroll
      for (int jj = 0; jj < 4; ++jj) {
        int g = wv + 8*jj;
        if (g >= 26) continue;
        int chain = (g < 13) ? 0 : 1;
        int uu = g - 13*chain;
        const uint8_t* sa8 = S8 + (chain ? X2B : X1B);
        const uint8_t* sb8 = S8 + (chain ? X1B : X2B);
        const int scl = chain ? CINV : RINV;
        const uint16_t* Acv = chain ? AG : AH;
        if (uu < 12) {
          long a0 = *(const long*)(sa8 + VX8(vbase + m32, h2*8));
          long a1 = *(const long*)(sa8 + VX8(vbase + m32, 16 + h2*8));
          long b0 = *(const long*)(sb8 + VX8(uu*32 + m32, h2*8));
          long b1 = *(const long*)(sb8 + VX8(uu*32 + m32, 16 + h2*8));
          f16v z = {}; z = MFP32(a0, b0, z); z = MFP32(a1, b1, z);
          #pragma unroll
          for (int k = 0; k < 2; ++k) {
            if (k < kmax) {
              const uint16_t* spt = S + scl + vbase + 16*k + 4*h2;
              uint32_t sAB = *(const uint32_t*)(spt);
              uint32_t sCD = *(const uint32_t*)(spt + 2);
              uint32_t sEF = *(const uint32_t*)(spt + 8);
              uint32_t sGH = *(const uint32_t*)(spt + 10);
              uint32_t C0 = cvtpk(E2(z[8*k+0])*bfLO(sAB), E2(z[8*k+1])*bfHI(sAB));
              uint32_t C1 = cvtpk(E2(z[8*k+2])*bfLO(sCD), E2(z[8*k+3])*bfHI(sCD));
              uint32_t C2 = cvtpk(E2(z[8*k+4])*bfLO(sEF), E2(z[8*k+5])*bfHI(sEF));
              uint32_t C3 = cvtpk(E2(z[8*k+6])*bfLO(sGH), E2(z[8*k+7])*bfHI(sGH));
              pl32swap(C0, C2);
              pl32swap(C1, C3);
              union { uint32_t d[4]; s8v v8; } F;
              F.d[0] = C0; F.d[1] = C1; F.d[2] = C2; F.d[3] = C3;
              s8v a = ld8(Acv + m32*STRD + vbase + k*16 + h2*8);
              acc[jj] = MF32(a, F.v8, acc[jj]);
            }
          }
        } else {
          long bT = *(const long*)(sb8 + VX8(384 + r, q*8));
          uint2 td0, td1; td1.x = 0u; td1.y = 0u;
          {
            long a = *(const long*)(sa8 + VX8(vbase + r, q*8));
            f4v z4 = {}; z4 = MFP16(a, bT, z4);
            float p0 = E2(z4[0]) * bf2f(S[scl + vbase + q*4 + 0]);
            float p1 = E2(z4[1]) * bf2f(S[scl + vbase + q*4 + 1]);
            float p2 = E2(z4[2]) * bf2f(S[scl + vbase + q*4 + 2]);
            float p3 = E2(z4[3]) * bf2f(S[scl + vbase + q*4 + 3]);
            td0.x = cvtpk(p0,p1); td0.y = cvtpk(p2,p3);
          }
          if (!lastsb) {
            long a = *(const long*)(sa8 + VX8(vbase + 16 + r, q*8));
            f4v z4 = {}; z4 = MFP16(a, bT, z4);
            float p0 = E2(z4[0]) * bf2f(S[scl + vbase + 16 + q*4 + 0]);
            float p1 = E2(z4[1]) * bf2f(S[scl + vbase + 16 + q*4 + 1]);
            float p2 = E2(z4[2]) * bf2f(S[scl + vbase + 16 + q*4 + 2]);
            float p3 = E2(z4[3]) * bf2f(S[scl + vbase + 16 + q*4 + 3]);
            td1.x = cvtpk(p0,p1); td1.y = cvtpk(p2,p3);
          }
          const int src0 = (((q<<1)) & 3)*16 + r;
          const int src1 = (((q<<1)+1) & 3)*16 + r;
          uint32_t a0x = (uint32_t)__shfl((int)td0.x, src0);
          uint32_t a0y = (uint32_t)__shfl((int)td0.y, src0);
          uint32_t a1x = (uint32_t)__shfl((int)td1.x, src0);
          uint32_t a1y = (uint32_t)__shfl((int)td1.y, src0);
          uint32_t b0x = (uint32_t)__shfl((int)td0.x, src1);
          uint32_t b0y = (uint32_t)__shfl((int)td0.y, src1);
          uint32_t b1x = (uint32_t)__shfl((int)td1.x, src1);
          uint32_t b1y = (uint32_t)__shfl((int)td1.y, src1);
          const bool hi = (q >= 2);
          union { uint32_t u[4]; s8v v8; } B;
          B.u[0] = hi ? a1x : a0x;
          B.u[1] = hi ? a1y : a0y;
          B.u[2] = hi ? b1x : b0x;
          B.u[3] = hi ? b1y : b0y;
          #pragma unroll
          for (int mt2 = 0; mt2 < 2; ++mt2) {
            int koff = (lastsb && q >= 2) ? 0 : q*8;
            s8v a = ld8(Acv + (mt2*16 + r)*STRD + vbase + koff);
            f4v c4 = { acc[jj][4*mt2+0], acc[jj][4*mt2+1], acc[jj][4*mt2+2], acc[jj][4*mt2+3] };
            c4 = MF16(a, B.v8, c4);
            acc[jj][4*mt2+0]=c4[0]; acc[jj][4*mt2+1]=c4[1]; acc[jj][4*mt2+2]=c4[2]; acc[jj][4*mt2+3]=c4[3];
          }
        }
      }
      __builtin_amdgcn_s_setprio(0);
    } // sb
    __syncthreads();
    if (step == 0) {
      // epilogue phase i (reads only): acc = AL*X + OM*acc
      #pragma unroll
      for (int jj = 0; jj < 4; ++jj) {
        int g = wv + 8*jj;
        if (g >= 26) continue;
        int chain = (g < 13) ? 0 : 1;
        int uu = g - 13*chain;
        if (uu < 12) {
          int w = uu*32 + m32;
          #pragma unroll
          for (int e2 = 0; e2 < 16; ++e2) {
            int c = ROWF(e2);
            acc[jj][e2] = AL*bf2f(S[XCV + c*STRD + w]) + OM*acc[jj][e2];
          }
        } else {
          int w = 384 + r;
          #pragma unroll
          for (int mt2 = 0; mt2 < 2; ++mt2)
            #pragma unroll
            for (int e = 0; e < 4; ++e) {
              int c = mt2*16 + q*4 + e;
              acc[jj][4*mt2+e] = AL*bf2f(S[XCV + c*STRD + w]) + OM*acc[jj][4*mt2+e];
            }
        }
      }
      __syncthreads();
      // epilogue phase ii (writes): H1 -> XCV (in place), G1 -> GCV
      #pragma unroll
      for (int jj = 0; jj < 4; ++jj) {
        int g = wv + 8*jj;
        if (g >= 26) continue;
        int chain = (g < 13) ? 0 : 1;
        int uu = g - 13*chain;
        uint16_t* dst = S + (chain ? GCV : XCV);
        if (uu < 12) {
          int w = uu*32 + m32;
          #pragma unroll
          for (int e2 = 0; e2 < 16; ++e2) { int c = ROWF(e2); dst[c*STRD + w] = f2bf(acc[jj][e2]); }
        } else {
          int w = 384 + r;
          #pragma unroll
          for (int mt2 = 0; mt2 < 2; ++mt2)
            #pragma unroll
            for (int e = 0; e < 4; ++e) { int c = mt2*16 + q*4 + e; dst[c*STRD + w] = f2bf(acc[jj][4*mt2+e]); }
        }
      }
      __syncthreads();
    }
  } // step

  // ---------- MLP: two passes (chain0 -> gStage write; chain1 -> add). Weights from global. ----------
  // PREP A: H1 [c][408] -> Hv [v][32] bf16 (over dead fp8 x1/x2)
  for (int i = t; i < 12800; i += TT) { int v = i >> 5, c = i & 31; S[HV + VXA(v,c)] = S[XCV + c*STRD + v]; }
  __syncthreads();
  // H2'v = OM*acc (chain-0 units) -> F2V (over XCV region)
  #pragma unroll
  for (int jj = 0; jj < 4; ++jj) {
    int g = wv + 8*jj;
    if (g >= 13) continue;              // chain 0 only
    int uu = g;
    uint16_t* dst = S + F2V;
    if (uu < 12) {
      int w = uu*32 + m32;
      #pragma unroll
      for (int gg = 0; gg < 4; ++gg) {
        uint2 d;
        d.x = cvtpk(OM*acc[jj][4*gg+0], OM*acc[jj][4*gg+1]);
        d.y = cvtpk(OM*acc[jj][4*gg+2], OM*acc[jj][4*gg+3]);
        *(uint2*)(dst + VXA(w, 8*gg + 4*h2)) = d;
      }
    } else {
      int w = 384 + r;
      #pragma unroll
      for (int mt2 = 0; mt2 < 2; ++mt2) {
        uint2 d;
        d.x = cvtpk(OM*acc[jj][4*mt2+0], OM*acc[jj][4*mt2+1]);
        d.y = cvtpk(OM*acc[jj][4*mt2+2], OM*acc[jj][4*mt2+3]);
        *(uint2*)(dst + VXA(w, mt2*16 + q*4)) = d;
      }
    }
  }
  __syncthreads();

  float* oSl = gStage + (long)(n*12 + l)*12800;
  // ---- PASS A (wm1, + combined bias): m-units m = wv + 8*jm ----
  #pragma unroll
  for (int jm = 0; jm < 2; ++jm) {
    int m = wv + 8*jm;
    if (m < 12) {
      f16v z = {};
      #pragma unroll
      for (int p = 0; p < 3; ++p) {
        #pragma unroll
        for (int kk = 0; kk < 2; ++kk) {
          const float* wp = wm1 + m32*96 + p*32 + kk*16 + h2*8;
          float4 f0 = *(const float4*)(wp), f1 = *(const float4*)(wp+4);
          if (p == 0) {
            const float* wp2 = wm1 + m32*96 + 64 + kk*16 + h2*8;
            float4 g0 = *(const float4*)(wp2), g1 = *(const float4*)(wp2+4);
            f0.x += AL*g0.x; f0.y += AL*g0.y; f0.z += AL*g0.z; f0.w += AL*g0.w;
            f1.x += AL*g1.x; f1.y += AL*g1.y; f1.z += AL*g1.z; f1.w += AL*g1.w;
          }
          s8v a = packw8(f0, f1);
          s8v b;
          if (p == 0) b = jm ? (kk ? xf1b : xf0b) : (kk ? xf1a : xf0a);
          else        b = ld8(S + (p == 1 ? HV : F2V) + VXA(m*32 + m32, kk*16 + h2*8));
          z = MF32(a, b, z);
        }
      }
      int v = m*32 + m32;
      #pragma unroll
      for (int e2 = 0; e2 < 16; ++e2) { int o = ROWF(e2); oSl[o*400 + v] = z[e2] + bm1[o] + bm2[o]; }
    } else if (m < 14) {
      int mt = m - 12;
      f4v z4 = {};
      #pragma unroll
      for (int p = 0; p < 3; ++p) {
        const float* wp = wm1 + (mt*16 + r)*96 + p*32 + q*8;
        float4 f0 = *(const float4*)(wp), f1 = *(const float4*)(wp+4);
        if (p == 0) {
          const float* wp2 = wm1 + (mt*16 + r)*96 + 64 + q*8;
          float4 g0 = *(const float4*)(wp2), g1 = *(const float4*)(wp2+4);
          f0.x += AL*g0.x; f0.y += AL*g0.y; f0.z += AL*g0.z; f0.w += AL*g0.w;
          f1.x += AL*g1.x; f1.y += AL*g1.y; f1.z += AL*g1.z; f1.w += AL*g1.w;
        }
        s8v a = packw8(f0, f1);
        s8v b = (p == 0) ? xft : ld8(S + (p == 1 ? HV : F2V) + VXA(384 + r, q*8));
        z4 = MF16(a, b, z4);
      }
      #pragma unroll
      for (int e = 0; e < 4; ++e) { int o = mt*16 + q*4 + e; oSl[o*400 + 384 + r] = z4[e] + bm1[o] + bm2[o]; }
    }
  }
  __syncthreads();
  // ---- PREP B: G1 -> Hv ; G2'v (chain-1 units) -> F2V ----
  for (int i = t; i < 12800; i += TT) { int v = i >> 5, c = i & 31; S[HV + VXA(v,c)] = S[GCV + c*STRD + v]; }
  #pragma unroll
  for (int jj = 0; jj < 4; ++jj) {
    int g = wv + 8*jj;
    if (g < 13 || g >= 26) continue;    // chain 1 only
    int uu = g - 13;
    uint16_t* dst = S + F2V;
    if (uu < 12) {
      int w = uu*32 + m32;
      #pragma unroll
      for (int gg = 0; gg < 4; ++gg) {
        uint2 d;
        d.x = cvtpk(OM*acc[jj][4*gg+0], OM*acc[jj][4*gg+1]);
        d.y = cvtpk(OM*acc[jj][4*gg+2], OM*acc[jj][4*gg+3]);
        *(uint2*)(dst + VXA(w, 8*gg + 4*h2)) = d;
      }
    } else {
      int w = 384 + r;
      #pragma unroll
      for (int mt2 = 0; mt2 < 2; ++mt2) {
        uint2 d;
        d.x = cvtpk(OM*acc[jj][4*mt2+0], OM*acc[jj][4*mt2+1]);
        d.y = cvtpk(OM*acc[jj][4*mt2+2], OM*acc[jj][4*mt2+3]);
        *(uint2*)(dst + VXA(w, mt2*16 + q*4)) = d;
      }
    }
  }
  __syncthreads();
  // ---- PASS B (wm2, accumulate into gStage) ----
  #pragma unroll
  for (int jm = 0; jm < 2; ++jm) {
    int m = wv + 8*jm;
    if (m < 12) {
      f16v z = {};
      #pragma unroll
      for (int p = 0; p < 3; ++p) {
        #pragma unroll
        for (int kk = 0; kk < 2; ++kk) {
          const float* wp = wm2 + m32*96 + p*32 + kk*16 + h2*8;
          float4 f0 = *(const float4*)(wp), f1 = *(const float4*)(wp+4);
          if (p == 0) {
            const float* wp2 = wm2 + m32*96 + 64 + kk*16 + h2*8;
            float4 g0 = *(const float4*)(wp2), g1 = *(const float4*)(wp2+4);
            f0.x += AL*g0.x; f0.y += AL*g0.y; f0.z += AL*g0.z; f0.w += AL*g0.w;
            f1.x += AL*g1.x; f1.y += AL*g1.y; f1.z += AL*g1.z; f1.w += AL*g1.w;
          }
          s8v a = packw8(f0, f1);
          s8v b;
          if (p == 0) b = jm ? (kk ? xf1b : xf0b) : (kk ? xf1a : xf0a);
          else        b = ld8(S + (p == 1 ? HV : F2V) + VXA(m*32 + m32, kk*16 + h2*8));
          z = MF32(a, b, z);
        }
      }
      int v = m*32 + m32;
      #pragma unroll
      for (int e2 = 0; e2 < 16; ++e2) { int o = ROWF(e2); oSl[o*400 + v] += z[e2]; }
    } else if (m < 14) {
      int mt = m - 12;
      f4v z4 = {};
      #pragma unroll
      for (int p = 0; p < 3; ++p) {
        const float* wp = wm2 + (mt*16 + r)*96 + p*32 + q*8;
        float4 f0 = *(const float4*)(wp), f1 = *(const float4*)(wp+4);
        if (p == 0) {
          const float* wp2 = wm2 + (mt*16 + r)*96 + 64 + q*8;
          float4 g0 = *(const float4*)(wp2), g1 = *(const float4*)(wp2+4);
          f0.x += AL*g0.x; f0.y += AL*g0.y; f0.z += AL*g0.z; f0.w += AL*g0.w;
          f1.x += AL*g1.x; f1.y += AL*g1.y; f1.z += AL*g1.z; f1.w += AL*g1.w;
        }
        s8v a = packw8(f0, f1);
        s8v b = (p == 0) ? xft : ld8(S + (p == 1 ? HV : F2V) + VXA(384 + r, q*8));
        z4 = MF16(a, b, z4);
      }
      #pragma unroll
      for (int e = 0; e < 4; ++e) { int o = mt*16 + q*4 + e; oSl[o*400 + 384 + r] += z4[e]; }
    }
  }
}

// Plain transpose kernel: gStage[n][l][o][v] -> out[n][o][v][l] (both sides coalesced)
__global__ __launch_bounds__(256) void finT(float* __restrict__ out) {
  int idx = blockIdx.x*256 + threadIdx.x;
  int n = idx / 12800, ov = idx - n*12800;
  const float* src = gStage + (long)n*153600 + ov;
  float vals[12];
  #pragma unroll
  for (int l = 0; l < 12; ++l) vals[l] = src[(long)l*12800];
  float4* dst = (float4*)(out + (long)idx*12);
  dst[0] = make_float4(vals[0],vals[1],vals[2],vals[3]);
  dst[1] = make_float4(vals[4],vals[5],vals[6],vals[7]);
  dst[2] = make_float4(vals[8],vals[9],vals[10],vals[11]);
}

extern "C" void kernel_launch(void* const* d_in, const int* in_sizes, int n_in,
                              void* d_out, int out_size, void* d_ws, size_t ws_size,
                              hipStream_t stream) {
  (void)in_sizes; (void)n_in; (void)out_size; (void)d_ws; (void)ws_size;
  dymix<<<dim3(384), dim3(TT), 0, stream>>>(
      (const float*)d_in[0],
      (const float*)d_in[1], (const float*)d_in[2],
      (const float*)d_in[3], (const float*)d_in[4],
      (const float*)d_in[5], (const float*)d_in[6],
      (const float*)d_in[7], (const float*)d_in[8]);
  finT<<<dim3(1600), dim3(256), 0, stream>>>((float*)d_out);
}